// Round 7
// baseline (162.248 us; speedup 1.0000x reference)
//
#include <hip/hip_runtime.h>

// ---------------------------------------------------------------------------
// NNSensorResponse: out[s,t] = sum_{b,n} sigmoid(MLPp(x))*MLPa(x)*mask * gauss(t-z)
// B=4,N=8000 (BN=32000), F_IN=3, HID=128, S=1024, T=1024, sigma runtime (=5.0).
// Gaussian band-limited (sigma=5 -> +-31 ticks): 16 buckets of 64-tick
// granularity, each owning a 128-tick span. Hp/Ha/GT stored in MFMA-fragment
// order, bucket-sorted (k_prep); k_main writes private partial planes P;
// k_reduce sums <=8 contributors per out element.
// R15 = R14 + k_main de-staged: Hp/Ha LDS staging + ALL main-loop barriers
// removed. Evidence: R14's counters show nothing >29% utilized (MFMA-busy
// ~9.6us, LDS ~7us, VALU ~13us of a 47us wall) -> serial latency chain, not a
// throughput limit. A chunk's Hp+Ha+GT = 24KB and all 8 waves read identical
// addresses -> L1-resident pattern GT already uses. Staging to LDS (vmcnt
// drain + ds_write + barrier + ds_read) is pure serial overhead (attn lesson:
// dropping LDS staging of cache-fit data was +26%). Waves now run fully
// independent; LDS keeps only Rsp (10KB, wave-private, no barrier).
// R14 kept: bucket-flip load balance (y>=4 -> bk=15-bk), partial planes,
// sort/prep/reduce verbatim.
// ---------------------------------------------------------------------------

#define BN_E   32000
#define NBLK   125          // BN_E / 256
#define HIDW   128
#define S_DIM  1024
#define T_DIM  1024
#define NBKT   16
#define KSPL   4
#define MAXPAD (BN_E + NBKT * 31)        // max padded list length (32496)
#define MAXCG  ((MAXPAD + 31) / 32)      // max 32-electron chunks (1016)
#define INV_SQRT_2PI 0.3989422804f

typedef __attribute__((ext_vector_type(8))) unsigned short u16x8;
typedef __attribute__((ext_vector_type(8))) __bf16         bf16x8;
typedef __attribute__((ext_vector_type(4))) float          f32x4;

static __device__ __forceinline__ unsigned short f2bf(float f) {
    union { float f; unsigned int u; } v; v.f = f;
    unsigned int r = v.u + 0x7FFFu + ((v.u >> 16) & 1u);   // RNE, inputs finite
    return (unsigned short)(r >> 16);
}

static __device__ __forceinline__ f32x4 mfma16(u16x8 a, u16x8 b, f32x4 c) {
    return __builtin_amdgcn_mfma_f32_16x16x32_bf16(
        __builtin_bit_cast(bf16x8, a), __builtin_bit_cast(bf16x8, b), c, 0, 0, 0);
}

static __device__ __forceinline__ int bucket_of(float z) {
    int b = (int)floorf((z - 31.f) * (1.f / 64.f));
    return min(max(b, 0), NBKT - 1);
}

// ---------------- sort stage 1: block hist ---------------------------------
__global__ __launch_bounds__(256) void k_count(const float* __restrict__ z,
                                               int* __restrict__ bc) {
    int bx = blockIdx.x;
    __shared__ int h[NBKT];
    if (threadIdx.x < NBKT) h[threadIdx.x] = 0;
    __syncthreads();
    int e = bx * 256 + threadIdx.x;   // BN_E % 256 == 0
    atomicAdd(&h[bucket_of(z[e])], 1);
    __syncthreads();
    if (threadIdx.x < NBKT) bc[bx * NBKT + threadIdx.x] = h[threadIdx.x];
}

// ---------------- sort stage 2: fused scan+scatter. grid: NBLK x 256 --------
__global__ __launch_bounds__(256) void k_fillscan(const float* __restrict__ z,
                                                  const int* __restrict__ bc,
                                                  int* __restrict__ meta,
                                                  int* __restrict__ list) {
    __shared__ int part[16][16];     // [seg][b]
    __shared__ int segoff[16][16];
    __shared__ int cntL[NBKT], pstartL[NBKT], baseL[NBKT], h[NBKT];
    int t = threadIdx.x, b = t & 15, seg = t >> 4;    // 16 segs x 8 blocks
    int v[8]; int sum = 0;
#pragma unroll
    for (int i = 0; i < 8; ++i) {
        int blk = seg * 8 + i;
        v[i] = (blk < NBLK) ? bc[blk * NBKT + b] : 0;
        sum += v[i];
    }
    part[seg][b] = sum;
    if (t < NBKT) h[t] = 0;
    __syncthreads();
    if (t < NBKT) {                  // t = bucket
        int run = 0;
        for (int s = 0; s < 16; ++s) { segoff[s][t] = run; run += part[s][t]; }
        cntL[t] = run;
    }
    __syncthreads();
    if (t == 0) {
        int s = 0;
        for (int i = 0; i < NBKT; ++i) {
            pstartL[i] = s;
            s += ((cntL[i] + 31) >> 5) << 5;          // padded bucket length
        }
        if (blockIdx.x == 0) {
            for (int i = 0; i < NBKT; ++i) { meta[i] = cntL[i]; meta[32 + i] = pstartL[i]; }
            meta[48] = s;
        }
    }
    __syncthreads();
    if (t < NBKT) {                  // own base for this block
        int me = blockIdx.x;
        int run = segoff[me >> 3][t];
        for (int k = 0; k < (me & 7); ++k)
            run += bc[((me >> 3) * 8 + k) * NBKT + t];
        baseL[t] = pstartL[t] + run;
    }
    __syncthreads();
    int e = blockIdx.x * 256 + t;
    int b2 = bucket_of(z[e]);
    int r = atomicAdd(&h[b2], 1);
    list[baseL[b2] + r] = e;
}

// ---------------- prep: fragment-ordered Hp/Ha/GT + W2 shuffle --------------
// blocks [0, MAXCG): one per 32-electron sorted chunk.
//   Hp/Ha chunk (4096 shorts): unit u = kq*32 + e holds H[e][k=kq*8..+7].
//   GT chunk (4096 shorts): unit u=(n8*4+q)*16+c holds G[t=n8*16+c][e=q*8..+7].
// blocks [MAXCG, MAXCG+128): W2 -> MFMA fragment order (coalesced in s).
__global__ __launch_bounds__(256) void k_prep(
    const float* __restrict__ x, const float* __restrict__ zg,
    const float* __restrict__ maskg, const float* __restrict__ sigp,
    const float* __restrict__ Wp1, const float* __restrict__ bp1,
    const float* __restrict__ Wa1, const float* __restrict__ ba1,
    const float* __restrict__ Wp2, const float* __restrict__ Wa2,
    const int* __restrict__ meta, const int* __restrict__ list,
    unsigned short* __restrict__ HpS, unsigned short* __restrict__ HaS,
    unsigned short* __restrict__ GT,
    unsigned short* __restrict__ WfP, unsigned short* __restrict__ WfA) {
    int bx = blockIdx.x;
    if (bx < MAXCG) {
        int tid = threadIdx.x;

        // W1/biases into LDS: [Wp1 384][bp1 128][Wa1 384][ba1 128] floats
        __shared__ float W1L[1024];
        __shared__ float zzL[32], cmL[32];
        __shared__ int metaL[33];    // [0..15]=cnt, [16..31]=pstart, [32]=total
        if (tid < 33) metaL[tid] = meta[tid < 16 ? tid : (tid < 32 ? tid + 16 : 48)];
        if (tid < 96)                        ((float4*)W1L)[tid]              = ((const float4*)Wp1)[tid];
        else if (tid < 128)                  ((float4*)(W1L + 384))[tid - 96] = ((const float4*)bp1)[tid - 96];
        else if (tid < 224)                  ((float4*)(W1L + 512))[tid - 128]= ((const float4*)Wa1)[tid - 128];
        else                                 ((float4*)(W1L + 896))[tid - 224]= ((const float4*)ba1)[tid - 224];
        __syncthreads();

        int pos0 = bx * 32;
        if (pos0 >= metaL[32]) return;
        int b = 15;
        while (metaL[16 + b] > pos0) --b;     // LDS search, chunk never crosses bucket
        int tb = b * 64, cnt = metaL[b], pstart = metaL[16 + b];

        if (tid < 32) {
            int pos = pos0 + tid;
            bool real = (pos - pstart) < cnt;
            int ev = real ? list[pos] : 0;
            float sigma = sigp[0];
            zzL[tid] = real ? zg[ev] : 0.f;
            cmL[tid] = real ? (INV_SQRT_2PI / sigma) * maskg[ev] : 0.f;
        }

        // ---- hidden states (fragment order, coalesced 512B store segments) ----
        {
            int e_l = tid & 31, part = tid >> 5;      // j = part*16 + i
            int pos = pos0 + e_l;
            bool real = (pos - pstart) < cnt;
            int ev = real ? list[pos] : 0;
            float x0 = 0.f, x1 = 0.f, x2 = 0.f;
            if (real) { x0 = x[ev * 3]; x1 = x[ev * 3 + 1]; x2 = x[ev * 3 + 2]; }
            unsigned short hp[16], ha[16];
#pragma unroll
            for (int i = 0; i < 16; ++i) {
                int j = part * 16 + i;
                float hv = x0 * W1L[j] + x1 * W1L[128 + j] + x2 * W1L[256 + j] + W1L[384 + j];
                float av = x0 * W1L[512 + j] + x1 * W1L[640 + j] + x2 * W1L[768 + j] + W1L[896 + j];
                hp[i] = real ? f2bf(fmaxf(hv, 0.f)) : (unsigned short)0;
                ha[i] = real ? f2bf(fmaxf(av, 0.f)) : (unsigned short)0;
            }
#pragma unroll
            for (int h2 = 0; h2 < 2; ++h2) {
                int u = (2 * part + h2) * 32 + e_l;   // kq = k0>>3 = 2*part+h2
                *(uint4*)&HpS[(size_t)bx * 4096 + u * 8] = ((uint4*)hp)[h2];
                *(uint4*)&HaS[(size_t)bx * 4096 + u * 8] = ((uint4*)ha)[h2];
            }
        }
        __syncthreads();   // zzL/cmL ready

        // ---- Gaussian tile (fragment order): 2 units x 8 electrons ----
        {
            float sigma = sigp[0];
            float nis2 = -1.f / (2.f * sigma * sigma);
#pragma unroll
            for (int uu = 0; uu < 2; ++uu) {
                int u = tid * 2 + uu;                 // 0..511
                int n8 = u >> 6, q = (u >> 4) & 3, c = u & 15;
                float tt = (float)(tb + n8 * 16 + c);
                unsigned short g8[8];
#pragma unroll
                for (int j = 0; j < 8; ++j) {
                    int e = q * 8 + j;
                    float d = tt - zzL[e];
                    g8[j] = f2bf(cmL[e] * __expf(d * d * nis2));
                }
                *(uint4*)&GT[(size_t)bx * 4096 + u * 8] = *(uint4*)g8;
            }
        }
    } else {
        int bid = bx - MAXCG;                       // 0..127
        const float* src = (bid & 64) ? Wa2 : Wp2;
        unsigned short* dst = (bid & 64) ? WfA : WfP;
        int rem = bid & 63;
        int kq = rem >> 2;                          // ks*4+q
        int s  = (rem & 3) * 256 + threadIdx.x;
        int ks = kq >> 2, q = kq & 3;
        unsigned short fr[8];
#pragma unroll
        for (int j = 0; j < 8; ++j)
            fr[j] = f2bf(src[(ks * 32 + q * 8 + j) * S_DIM + s]);
        ((u16x8*)dst)[kq * S_DIM + s] = *(u16x8*)fr;
    }
}

// ---------------- main fused kernel --------------------------------------
// grid: (NBKT*KSPL = 64, 8 s_tiles of 128), 512 threads (8 waves), 2 blk/CU.
// NO LDS staging, NO main-loop barriers: Hp/Ha fragments read direct from
// global (all 8 waves read identical addresses -> L1-shared; chunk working
// set Hp+Ha+GT = 24KB fits L1). LDS holds only Rsp (wave-private rows,
// same-wave DS ordering -> barrier-free). 16 waves/CU run independently.
// Load balance: y>=4 flips bk -> 15-bk (heavy bucket pairs with light one).
__global__ __launch_bounds__(512, 4) void k_main(
    const unsigned short* __restrict__ HpS, const unsigned short* __restrict__ HaS,
    const unsigned short* __restrict__ WfP, const unsigned short* __restrict__ WfA,
    const float* __restrict__ bp2, const float* __restrict__ ba2,
    const int* __restrict__ meta, const unsigned short* __restrict__ GT,
    float* __restrict__ P) {

    const int bk0    = blockIdx.x / KSPL;
    const int kspl   = blockIdx.x % KSPL;
    const int y      = blockIdx.y;
    const int bk     = (y < 4) ? bk0 : (NBKT - 1 - bk0);   // pair heavy+light
    const int s0     = y * 128;
    const int cnt    = meta[bk];
    const int pstart = meta[32 + bk];          // padded, multiple of 32
    const int nch    = (cnt + 31) >> 5;
    const int per    = (nch + KSPL - 1) / KSPL;
    const int c0     = kspl * per;
    const int c1     = min(nch, c0 + per);

    const int tid = threadIdx.x;
    const int w = tid >> 6, l = tid & 63, q = l >> 4, c = l & 15;
    const f32x4 z4 = { 0.f, 0.f, 0.f, 0.f };
    float* Pp = P + (size_t)((bk * KSPL + kspl) * 8 + y) * 16384;

    if (c0 >= c1) {                            // uniform across block
        f32x4* p4 = (f32x4*)Pp;
#pragma unroll
        for (int i = 0; i < 8; ++i) p4[i * 512 + tid] = z4;
        return;
    }

    // LDS: Rsp transpose only (10 KB)
    __shared__ __align__(16) unsigned short RspL[128 * 40];

    // W2 fragments for this wave's 16 s-columns: 8 coalesced 16B loads.
    const u16x8* WfPv = (const u16x8*)WfP;
    const u16x8* WfAv = (const u16x8*)WfA;
    const int sg = s0 + w * 16 + c;
    u16x8 wP[4], wA[4];
#pragma unroll
    for (int ks = 0; ks < 4; ++ks) {
        wP[ks] = WfPv[(ks * 4 + q) * S_DIM + sg];
        wA[ks] = WfAv[(ks * 4 + q) * S_DIM + sg];
    }
    const float bp2v = bp2[sg];
    const float ba2v = ba2[sg];

    f32x4 acc2[8];
#pragma unroll
    for (int n8 = 0; n8 < 8; ++n8) acc2[n8] = z4;

    const u16x8* Hp8 = (const u16x8*)HpS;
    const u16x8* Ha8 = (const u16x8*)HaS;
    const int cgBase = pstart >> 5;            // first chunk index of bucket

    for (int ci = c0; ci < c1; ++ci) {
        const size_t ub = (size_t)(cgBase + ci) * 512;   // chunk base (u16x8 units)

        // GT B-fragments direct from global (all 8 waves share -> L1 hot)
        const unsigned short* gt = GT + (size_t)(cgBase + ci) * 4096;
        u16x8 bfr[8];
#pragma unroll
        for (int n8 = 0; n8 < 8; ++n8)
            bfr[n8] = *(const u16x8*)&gt[((n8 * 4 + q) * 16 + c) * 8];

        // GEMM1: C1[e][s] = H[e][k] @ W2[k][s]  (M=e 32, N=s 16/wave, K=128)
        // A-fragments direct from global: 4 x 256B segments per wave-load,
        // identical addresses across the block's 8 waves (L1-shared).
        f32x4 aP[2], aA[2];
        aP[0] = z4; aP[1] = z4; aA[0] = z4; aA[1] = z4;
#pragma unroll
        for (int ks = 0; ks < 4; ++ks) {
            u16x8 hp0 = Hp8[ub + (ks * 4 + q) * 32 + c];
            u16x8 hp1 = Hp8[ub + (ks * 4 + q) * 32 + c + 16];
            u16x8 ha0 = Ha8[ub + (ks * 4 + q) * 32 + c];
            u16x8 ha1 = Ha8[ub + (ks * 4 + q) * 32 + c + 16];
            aP[0] = mfma16(hp0, wP[ks], aP[0]);
            aP[1] = mfma16(hp1, wP[ks], aP[1]);
            aA[0] = mfma16(ha0, wA[ks], aA[0]);
            aA[1] = mfma16(ha1, wA[ks], aA[1]);
        }

        // epilogue1: rsp = sigmoid(p+bp2)*(a+ba2); C-layout -> RspL[s][e]
        // rows wave-private; DS ops in-order per wave -> no barrier needed
#pragma unroll
        for (int m = 0; m < 2; ++m) {
            f32x4 pp = aP[m], aa = aA[m];
            unsigned long long pk = 0;
#pragma unroll
            for (int r = 0; r < 4; ++r) {
                float pr = pp[r] + bp2v;
                float ar = aa[r] + ba2v;
                float sg2 = __builtin_amdgcn_rcpf(1.f + __expf(-pr));
                pk |= (unsigned long long)f2bf(sg2 * ar) << (16 * r);
            }
            *(unsigned long long*)&RspL[(w * 16 + c) * 40 + m * 16 + q * 4] = pk;
        }

        // GEMM2: out[s][t] += Rsp[s][e] @ G[e][t]  (M=s 16/wave, N=t 128, K=32)
        u16x8 afr = *(const u16x8*)&RspL[(w * 16 + c) * 40 + q * 8];
#pragma unroll
        for (int n8 = 0; n8 < 8; ++n8)
            acc2[n8] = mfma16(afr, bfr[n8], acc2[n8]);
    }

    // epilogue2: plain streaming stores to private partial plane.
#pragma unroll
    for (int n8 = 0; n8 < 8; ++n8) {
        int tl = n8 * 16 + c;
        int sl = w * 16 + q * 4;
#pragma unroll
        for (int r = 0; r < 4; ++r)
            Pp[(sl + r) * 128 + tl] = acc2[n8][r];
    }
}

// ---------------- reduce: out[s,t] = sum of <=8 partial contributions -------
// grid: 1024 x 256. thread -> one float4 of out (s = idx>>8, t0 = (idx&255)*4).
// Contributors: bucket bkA = t0>>6 (local col t0&63) and bkA-1 (col 64+(t0&63)),
// each x KSPL ksplit planes. All loads 16B coalesced; writes all of out.
__global__ __launch_bounds__(256) void k_reduce(const float* __restrict__ P,
                                                float* __restrict__ out) {
    int idx = blockIdx.x * 256 + threadIdx.x;     // 0..262143
    int t0  = (idx & 255) << 2;
    int s   = idx >> 8;
    int bkA = t0 >> 6;
    int colA = t0 & 63;
    int y    = s >> 7;
    int sl   = s & 127;
    const f32x4* P4 = (const f32x4*)P;
    f32x4 acc = { 0.f, 0.f, 0.f, 0.f };
#pragma unroll
    for (int k = 0; k < KSPL; ++k) {
        f32x4 v = P4[((size_t)(bkA * KSPL + k) * 8 + y) * 4096 + sl * 32 + (colA >> 2)];
        acc[0] += v[0]; acc[1] += v[1]; acc[2] += v[2]; acc[3] += v[3];
    }
    if (bkA > 0) {
        int colB = 64 + colA;
#pragma unroll
        for (int k = 0; k < KSPL; ++k) {
            f32x4 v = P4[((size_t)((bkA - 1) * KSPL + k) * 8 + y) * 4096 + sl * 32 + (colB >> 2)];
            acc[0] += v[0]; acc[1] += v[1]; acc[2] += v[2]; acc[3] += v[3];
        }
    }
    ((f32x4*)out)[idx] = acc;
}

// ---------------- launch ----------------

extern "C" void kernel_launch(void* const* d_in, const int* in_sizes, int n_in,
                              void* d_out, int out_size, void* d_ws, size_t ws_size,
                              hipStream_t stream) {
    const float* x    = (const float*)d_in[0];
    const float* zp   = (const float*)d_in[1];
    const float* mask = (const float*)d_in[2];
    const float* Wp1  = (const float*)d_in[3];
    const float* bp1  = (const float*)d_in[4];
    const float* Wp2  = (const float*)d_in[5];
    const float* bp2  = (const float*)d_in[6];
    const float* Wa1  = (const float*)d_in[7];
    const float* ba1  = (const float*)d_in[8];
    const float* Wa2  = (const float*)d_in[9];
    const float* ba2  = (const float*)d_in[10];
    const float* sig  = (const float*)d_in[11];

    char* ws = (char*)d_ws;
    unsigned short* HpS  = (unsigned short*)(ws);                      // 8,323,072 B
    unsigned short* HaS  = (unsigned short*)(ws + 8323072);            // 8,323,072 B
    unsigned short* WfP  = (unsigned short*)(ws + 16646144);           //   262,144 B
    unsigned short* WfA  = (unsigned short*)(ws + 16908288);           //   262,144 B
    int*            meta = (int*)(ws + 17170432);                      //       256 B
    int*            list = (int*)(ws + 17170688);                      //   130,048 B
    int*            bc   = (int*)(ws + 17300736);                      //     8,000 B
    unsigned short* GT   = (unsigned short*)(ws + 17308736);           // 8,323,072 B
    float*          P    = (float*)(ws + 25631808);                    // 33,554,432 B
    // total ws ~59.2 MB

    k_count<<<NBLK, 256, 0, stream>>>(zp, bc);
    k_fillscan<<<NBLK, 256, 0, stream>>>(zp, bc, meta, list);
    k_prep<<<MAXCG + 128, 256, 0, stream>>>(x, zp, mask, sig,
                                            Wp1, bp1, Wa1, ba1, Wp2, Wa2,
                                            meta, list, HpS, HaS, GT, WfP, WfA);
    k_main<<<dim3(NBKT * KSPL, 8, 1), 512, 0, stream>>>(
        HpS, HaS, WfP, WfA, bp2, ba2, meta, GT, P);
    k_reduce<<<1024, 256, 0, stream>>>(P, (float*)d_out);
}

// Round 8
// 139.149 us; speedup vs baseline: 1.1660x; 1.1660x over previous
//
#include <hip/hip_runtime.h>

// ---------------------------------------------------------------------------
// NNSensorResponse: out[s,t] = sum_{b,n} sigmoid(MLPp(x))*MLPa(x)*mask * gauss(t-z)
// B=4,N=8000 (BN=32000), F_IN=3, HID=128, S=1024, T=1024, sigma runtime (=5.0).
// Gaussian band-limited (sigma=5 -> +-31 ticks): 16 buckets of 64-tick
// granularity, each owning a 128-tick span. Hp/Ha/GT stored in MFMA-fragment
// order, bucket-sorted (k_prep); k_main stages Hp/Ha chunks to LDS, writes
// private partial planes P; k_reduce sums <=8 contributors per out element.
// R16 = R14 with the prefetch ISSUE moved to after the barrier.
// Evidence: R14 budgets: LDS 17us(36%), MFMA 9.6us(20%), VALU 13us(29%) of a
// 47us wall -> serial stall, not throughput. The stall: R8-R14 issued the
// next-chunk global loads ~20 instrs BEFORE __syncthreads(); the compiler's
// s_waitcnt vmcnt(0) before s_barrier forces those loads to complete THERE ->
// every iteration eats full L2 latency (~500-900cy of ~3400cy/iter). Fix:
// ds_write staged regs -> barrier (vmcnt already drained, only cheap lgkm) ->
// issue next loads -> compute (full-iteration slack). Pure reorder; regs,
// LDS, barriers, hazards identical to R14. R15 (de-staged, direct-global A)
// regressed 47->66us: L1 BW < LDS BW; staging confirmed necessary.
// R14 kept: bucket-flip load balance (y>=4 -> bk=15-bk), partial planes P,
// sort/prep/reduce verbatim.
// ---------------------------------------------------------------------------

#define BN_E   32000
#define NBLK   125          // BN_E / 256
#define HIDW   128
#define S_DIM  1024
#define T_DIM  1024
#define NBKT   16
#define KSPL   4
#define MAXPAD (BN_E + NBKT * 31)        // max padded list length (32496)
#define MAXCG  ((MAXPAD + 31) / 32)      // max 32-electron chunks (1016)
#define INV_SQRT_2PI 0.3989422804f

typedef __attribute__((ext_vector_type(8))) unsigned short u16x8;
typedef __attribute__((ext_vector_type(8))) __bf16         bf16x8;
typedef __attribute__((ext_vector_type(4))) float          f32x4;

static __device__ __forceinline__ unsigned short f2bf(float f) {
    union { float f; unsigned int u; } v; v.f = f;
    unsigned int r = v.u + 0x7FFFu + ((v.u >> 16) & 1u);   // RNE, inputs finite
    return (unsigned short)(r >> 16);
}

static __device__ __forceinline__ f32x4 mfma16(u16x8 a, u16x8 b, f32x4 c) {
    return __builtin_amdgcn_mfma_f32_16x16x32_bf16(
        __builtin_bit_cast(bf16x8, a), __builtin_bit_cast(bf16x8, b), c, 0, 0, 0);
}

static __device__ __forceinline__ int bucket_of(float z) {
    int b = (int)floorf((z - 31.f) * (1.f / 64.f));
    return min(max(b, 0), NBKT - 1);
}

// ---------------- sort stage 1: block hist ---------------------------------
__global__ __launch_bounds__(256) void k_count(const float* __restrict__ z,
                                               int* __restrict__ bc) {
    int bx = blockIdx.x;
    __shared__ int h[NBKT];
    if (threadIdx.x < NBKT) h[threadIdx.x] = 0;
    __syncthreads();
    int e = bx * 256 + threadIdx.x;   // BN_E % 256 == 0
    atomicAdd(&h[bucket_of(z[e])], 1);
    __syncthreads();
    if (threadIdx.x < NBKT) bc[bx * NBKT + threadIdx.x] = h[threadIdx.x];
}

// ---------------- sort stage 2: fused scan+scatter. grid: NBLK x 256 --------
__global__ __launch_bounds__(256) void k_fillscan(const float* __restrict__ z,
                                                  const int* __restrict__ bc,
                                                  int* __restrict__ meta,
                                                  int* __restrict__ list) {
    __shared__ int part[16][16];     // [seg][b]
    __shared__ int segoff[16][16];
    __shared__ int cntL[NBKT], pstartL[NBKT], baseL[NBKT], h[NBKT];
    int t = threadIdx.x, b = t & 15, seg = t >> 4;    // 16 segs x 8 blocks
    int v[8]; int sum = 0;
#pragma unroll
    for (int i = 0; i < 8; ++i) {
        int blk = seg * 8 + i;
        v[i] = (blk < NBLK) ? bc[blk * NBKT + b] : 0;
        sum += v[i];
    }
    part[seg][b] = sum;
    if (t < NBKT) h[t] = 0;
    __syncthreads();
    if (t < NBKT) {                  // t = bucket
        int run = 0;
        for (int s = 0; s < 16; ++s) { segoff[s][t] = run; run += part[s][t]; }
        cntL[t] = run;
    }
    __syncthreads();
    if (t == 0) {
        int s = 0;
        for (int i = 0; i < NBKT; ++i) {
            pstartL[i] = s;
            s += ((cntL[i] + 31) >> 5) << 5;          // padded bucket length
        }
        if (blockIdx.x == 0) {
            for (int i = 0; i < NBKT; ++i) { meta[i] = cntL[i]; meta[32 + i] = pstartL[i]; }
            meta[48] = s;
        }
    }
    __syncthreads();
    if (t < NBKT) {                  // own base for this block
        int me = blockIdx.x;
        int run = segoff[me >> 3][t];
        for (int k = 0; k < (me & 7); ++k)
            run += bc[((me >> 3) * 8 + k) * NBKT + t];
        baseL[t] = pstartL[t] + run;
    }
    __syncthreads();
    int e = blockIdx.x * 256 + t;
    int b2 = bucket_of(z[e]);
    int r = atomicAdd(&h[b2], 1);
    list[baseL[b2] + r] = e;
}

// ---------------- prep: fragment-ordered Hp/Ha/GT + W2 shuffle --------------
// blocks [0, MAXCG): one per 32-electron sorted chunk.
//   Hp/Ha chunk (4096 shorts): unit u = kq*32 + e holds H[e][k=kq*8..+7].
//   GT chunk (4096 shorts): unit u=(n8*4+q)*16+c holds G[t=n8*16+c][e=q*8..+7].
// blocks [MAXCG, MAXCG+128): W2 -> MFMA fragment order (coalesced in s).
__global__ __launch_bounds__(256) void k_prep(
    const float* __restrict__ x, const float* __restrict__ zg,
    const float* __restrict__ maskg, const float* __restrict__ sigp,
    const float* __restrict__ Wp1, const float* __restrict__ bp1,
    const float* __restrict__ Wa1, const float* __restrict__ ba1,
    const float* __restrict__ Wp2, const float* __restrict__ Wa2,
    const int* __restrict__ meta, const int* __restrict__ list,
    unsigned short* __restrict__ HpS, unsigned short* __restrict__ HaS,
    unsigned short* __restrict__ GT,
    unsigned short* __restrict__ WfP, unsigned short* __restrict__ WfA) {
    int bx = blockIdx.x;
    if (bx < MAXCG) {
        int tid = threadIdx.x;

        // W1/biases into LDS: [Wp1 384][bp1 128][Wa1 384][ba1 128] floats
        __shared__ float W1L[1024];
        __shared__ float zzL[32], cmL[32];
        __shared__ int metaL[33];    // [0..15]=cnt, [16..31]=pstart, [32]=total
        if (tid < 33) metaL[tid] = meta[tid < 16 ? tid : (tid < 32 ? tid + 16 : 48)];
        if (tid < 96)                        ((float4*)W1L)[tid]              = ((const float4*)Wp1)[tid];
        else if (tid < 128)                  ((float4*)(W1L + 384))[tid - 96] = ((const float4*)bp1)[tid - 96];
        else if (tid < 224)                  ((float4*)(W1L + 512))[tid - 128]= ((const float4*)Wa1)[tid - 128];
        else                                 ((float4*)(W1L + 896))[tid - 224]= ((const float4*)ba1)[tid - 224];
        __syncthreads();

        int pos0 = bx * 32;
        if (pos0 >= metaL[32]) return;
        int b = 15;
        while (metaL[16 + b] > pos0) --b;     // LDS search, chunk never crosses bucket
        int tb = b * 64, cnt = metaL[b], pstart = metaL[16 + b];

        if (tid < 32) {
            int pos = pos0 + tid;
            bool real = (pos - pstart) < cnt;
            int ev = real ? list[pos] : 0;
            float sigma = sigp[0];
            zzL[tid] = real ? zg[ev] : 0.f;
            cmL[tid] = real ? (INV_SQRT_2PI / sigma) * maskg[ev] : 0.f;
        }

        // ---- hidden states (fragment order, coalesced 512B store segments) ----
        {
            int e_l = tid & 31, part = tid >> 5;      // j = part*16 + i
            int pos = pos0 + e_l;
            bool real = (pos - pstart) < cnt;
            int ev = real ? list[pos] : 0;
            float x0 = 0.f, x1 = 0.f, x2 = 0.f;
            if (real) { x0 = x[ev * 3]; x1 = x[ev * 3 + 1]; x2 = x[ev * 3 + 2]; }
            unsigned short hp[16], ha[16];
#pragma unroll
            for (int i = 0; i < 16; ++i) {
                int j = part * 16 + i;
                float hv = x0 * W1L[j] + x1 * W1L[128 + j] + x2 * W1L[256 + j] + W1L[384 + j];
                float av = x0 * W1L[512 + j] + x1 * W1L[640 + j] + x2 * W1L[768 + j] + W1L[896 + j];
                hp[i] = real ? f2bf(fmaxf(hv, 0.f)) : (unsigned short)0;
                ha[i] = real ? f2bf(fmaxf(av, 0.f)) : (unsigned short)0;
            }
#pragma unroll
            for (int h2 = 0; h2 < 2; ++h2) {
                int u = (2 * part + h2) * 32 + e_l;   // kq = k0>>3 = 2*part+h2
                *(uint4*)&HpS[(size_t)bx * 4096 + u * 8] = ((uint4*)hp)[h2];
                *(uint4*)&HaS[(size_t)bx * 4096 + u * 8] = ((uint4*)ha)[h2];
            }
        }
        __syncthreads();   // zzL/cmL ready

        // ---- Gaussian tile (fragment order): 2 units x 8 electrons ----
        {
            float sigma = sigp[0];
            float nis2 = -1.f / (2.f * sigma * sigma);
#pragma unroll
            for (int uu = 0; uu < 2; ++uu) {
                int u = tid * 2 + uu;                 // 0..511
                int n8 = u >> 6, q = (u >> 4) & 3, c = u & 15;
                float tt = (float)(tb + n8 * 16 + c);
                unsigned short g8[8];
#pragma unroll
                for (int j = 0; j < 8; ++j) {
                    int e = q * 8 + j;
                    float d = tt - zzL[e];
                    g8[j] = f2bf(cmL[e] * __expf(d * d * nis2));
                }
                *(uint4*)&GT[(size_t)bx * 4096 + u * 8] = *(uint4*)g8;
            }
        }
    } else {
        int bid = bx - MAXCG;                       // 0..127
        const float* src = (bid & 64) ? Wa2 : Wp2;
        unsigned short* dst = (bid & 64) ? WfA : WfP;
        int rem = bid & 63;
        int kq = rem >> 2;                          // ks*4+q
        int s  = (rem & 3) * 256 + threadIdx.x;
        int ks = kq >> 2, q = kq & 3;
        unsigned short fr[8];
#pragma unroll
        for (int j = 0; j < 8; ++j)
            fr[j] = f2bf(src[(ks * 32 + q * 8 + j) * S_DIM + s]);
        ((u16x8*)dst)[kq * S_DIM + s] = *(u16x8*)fr;
    }
}

// ---------------- main fused kernel --------------------------------------
// grid: (NBKT*KSPL = 64, 8 s_tiles of 128), 512 threads (8 waves), 2 blk/CU.
// Double-buffered chunk stage, ONE barrier per chunk. KEY ORDER (R16):
//   ds_write staged regs -> __syncthreads (vmcnt already 0; only lgkm drain)
//   -> ISSUE next chunk's global loads -> compute (loads get a full
//   iteration of slack instead of 20 instructions).
// Load balance: y>=4 flips bk -> 15-bk (heavy bucket pairs with light one).
__global__ __launch_bounds__(512, 4) void k_main(
    const unsigned short* __restrict__ HpS, const unsigned short* __restrict__ HaS,
    const unsigned short* __restrict__ WfP, const unsigned short* __restrict__ WfA,
    const float* __restrict__ bp2, const float* __restrict__ ba2,
    const int* __restrict__ meta, const unsigned short* __restrict__ GT,
    float* __restrict__ P) {

    const int bk0    = blockIdx.x / KSPL;
    const int kspl   = blockIdx.x % KSPL;
    const int y      = blockIdx.y;
    const int bk     = (y < 4) ? bk0 : (NBKT - 1 - bk0);   // pair heavy+light
    const int s0     = y * 128;
    const int cnt    = meta[bk];
    const int pstart = meta[32 + bk];          // padded, multiple of 32
    const int nch    = (cnt + 31) >> 5;
    const int per    = (nch + KSPL - 1) / KSPL;
    const int c0     = kspl * per;
    const int c1     = min(nch, c0 + per);

    const int tid = threadIdx.x;
    const int w = tid >> 6, l = tid & 63, q = l >> 4, c = l & 15;
    const f32x4 z4 = { 0.f, 0.f, 0.f, 0.f };
    float* Pp = P + (size_t)((bk * KSPL + kspl) * 8 + y) * 16384;

    if (c0 >= c1) {                            // uniform across block
        f32x4* p4 = (f32x4*)Pp;
#pragma unroll
        for (int i = 0; i < 8; ++i) p4[i * 512 + tid] = z4;
        return;
    }

    // LDS: double-buffered Hp/Ha stage (32 KB) + Rsp transpose (10 KB)
    __shared__ __align__(16) uint4 HpL[1024];
    __shared__ __align__(16) uint4 HaL[1024];
    __shared__ __align__(16) unsigned short RspL[128 * 40];

    // W2 fragments for this wave's 16 s-columns: 8 coalesced 16B loads.
    const u16x8* WfPv = (const u16x8*)WfP;
    const u16x8* WfAv = (const u16x8*)WfA;
    const int sg = s0 + w * 16 + c;
    u16x8 wP[4], wA[4];
#pragma unroll
    for (int ks = 0; ks < 4; ++ks) {
        wP[ks] = WfPv[(ks * 4 + q) * S_DIM + sg];
        wA[ks] = WfAv[(ks * 4 + q) * S_DIM + sg];
    }
    const float bp2v = bp2[sg];
    const float ba2v = ba2[sg];

    f32x4 acc2[8];
#pragma unroll
    for (int n8 = 0; n8 < 8; ++n8) acc2[n8] = z4;

    const uint4* Hp4 = (const uint4*)HpS;
    const uint4* Ha4 = (const uint4*)HaS;
    const int cgBase = pstart >> 5;            // first chunk index of bucket

    // prologue: load chunk c0 into registers (completes before first ds_write)
    size_t cb = (size_t)(cgBase + c0) * 512;
    uint4 p = Hp4[cb + tid];
    uint4 a = Ha4[cb + tid];

    for (int ci = c0; ci < c1; ++ci) {
        const int buf = ((ci - c0) & 1) << 9;  // 0 / 512 uint4 offset
        HpL[buf + tid] = p;                    // vmcnt wait here ~0: loads had
        HaL[buf + tid] = a;                    //   a full iteration in flight
        __syncthreads();                       // drains only cheap lgkm

        // R16: issue next chunk's prefetch AFTER the barrier -> it stays in
        // flight across this whole iteration's compute, not 20 instructions.
        int nc = min(ci + 1, c1 - 1);
        cb = (size_t)(cgBase + nc) * 512;
        p = Hp4[cb + tid];
        a = Ha4[cb + tid];

        // GT B-fragments direct from global (all 8 waves share -> L1 hot)
        const unsigned short* gt = GT + (size_t)(cgBase + ci) * 4096;
        u16x8 bfr[8];
#pragma unroll
        for (int n8 = 0; n8 < 8; ++n8)
            bfr[n8] = *(const u16x8*)&gt[((n8 * 4 + q) * 16 + c) * 8];

        // GEMM1: C1[e][s] = H[e][k] @ W2[k][s]  (M=e 32, N=s 16/wave, K=128)
        const u16x8* StHp = (const u16x8*)(HpL + buf);
        const u16x8* StHa = (const u16x8*)(HaL + buf);
        f32x4 aP[2], aA[2];
        aP[0] = z4; aP[1] = z4; aA[0] = z4; aA[1] = z4;
#pragma unroll
        for (int ks = 0; ks < 4; ++ks) {
            u16x8 hp0 = StHp[(ks * 4 + q) * 32 + c];
            u16x8 hp1 = StHp[(ks * 4 + q) * 32 + c + 16];
            u16x8 ha0 = StHa[(ks * 4 + q) * 32 + c];
            u16x8 ha1 = StHa[(ks * 4 + q) * 32 + c + 16];
            aP[0] = mfma16(hp0, wP[ks], aP[0]);
            aP[1] = mfma16(hp1, wP[ks], aP[1]);
            aA[0] = mfma16(ha0, wA[ks], aA[0]);
            aA[1] = mfma16(ha1, wA[ks], aA[1]);
        }

        // epilogue1: rsp = sigmoid(p+bp2)*(a+ba2); C-layout -> RspL[s][e]
        // rows wave-private; DS ops in-order per wave -> no barrier needed
#pragma unroll
        for (int m = 0; m < 2; ++m) {
            f32x4 pp = aP[m], aa = aA[m];
            unsigned long long pk = 0;
#pragma unroll
            for (int r = 0; r < 4; ++r) {
                float pr = pp[r] + bp2v;
                float ar = aa[r] + ba2v;
                float sg2 = __builtin_amdgcn_rcpf(1.f + __expf(-pr));
                pk |= (unsigned long long)f2bf(sg2 * ar) << (16 * r);
            }
            *(unsigned long long*)&RspL[(w * 16 + c) * 40 + m * 16 + q * 4] = pk;
        }

        // GEMM2: out[s][t] += Rsp[s][e] @ G[e][t]  (M=s 16/wave, N=t 128, K=32)
        u16x8 afr = *(const u16x8*)&RspL[(w * 16 + c) * 40 + q * 8];
#pragma unroll
        for (int n8 = 0; n8 < 8; ++n8)
            acc2[n8] = mfma16(afr, bfr[n8], acc2[n8]);
    }

    // epilogue2: plain streaming stores to private partial plane.
#pragma unroll
    for (int n8 = 0; n8 < 8; ++n8) {
        int tl = n8 * 16 + c;
        int sl = w * 16 + q * 4;
#pragma unroll
        for (int r = 0; r < 4; ++r)
            Pp[(sl + r) * 128 + tl] = acc2[n8][r];
    }
}

// ---------------- reduce: out[s,t] = sum of <=8 partial contributions -------
// grid: 1024 x 256. thread -> one float4 of out (s = idx>>8, t0 = (idx&255)*4).
// Contributors: bucket bkA = t0>>6 (local col t0&63) and bkA-1 (col 64+(t0&63)),
// each x KSPL ksplit planes. All loads 16B coalesced; writes all of out.
__global__ __launch_bounds__(256) void k_reduce(const float* __restrict__ P,
                                                float* __restrict__ out) {
    int idx = blockIdx.x * 256 + threadIdx.x;     // 0..262143
    int t0  = (idx & 255) << 2;
    int s   = idx >> 8;
    int bkA = t0 >> 6;
    int colA = t0 & 63;
    int y    = s >> 7;
    int sl   = s & 127;
    const f32x4* P4 = (const f32x4*)P;
    f32x4 acc = { 0.f, 0.f, 0.f, 0.f };
#pragma unroll
    for (int k = 0; k < KSPL; ++k) {
        f32x4 v = P4[((size_t)(bkA * KSPL + k) * 8 + y) * 4096 + sl * 32 + (colA >> 2)];
        acc[0] += v[0]; acc[1] += v[1]; acc[2] += v[2]; acc[3] += v[3];
    }
    if (bkA > 0) {
        int colB = 64 + colA;
#pragma unroll
        for (int k = 0; k < KSPL; ++k) {
            f32x4 v = P4[((size_t)((bkA - 1) * KSPL + k) * 8 + y) * 4096 + sl * 32 + (colB >> 2)];
            acc[0] += v[0]; acc[1] += v[1]; acc[2] += v[2]; acc[3] += v[3];
        }
    }
    ((f32x4*)out)[idx] = acc;
}

// ---------------- launch ----------------

extern "C" void kernel_launch(void* const* d_in, const int* in_sizes, int n_in,
                              void* d_out, int out_size, void* d_ws, size_t ws_size,
                              hipStream_t stream) {
    const float* x    = (const float*)d_in[0];
    const float* zp   = (const float*)d_in[1];
    const float* mask = (const float*)d_in[2];
    const float* Wp1  = (const float*)d_in[3];
    const float* bp1  = (const float*)d_in[4];
    const float* Wp2  = (const float*)d_in[5];
    const float* bp2  = (const float*)d_in[6];
    const float* Wa1  = (const float*)d_in[7];
    const float* ba1  = (const float*)d_in[8];
    const float* Wa2  = (const float*)d_in[9];
    const float* ba2  = (const float*)d_in[10];
    const float* sig  = (const float*)d_in[11];

    char* ws = (char*)d_ws;
    unsigned short* HpS  = (unsigned short*)(ws);                      // 8,323,072 B
    unsigned short* HaS  = (unsigned short*)(ws + 8323072);            // 8,323,072 B
    unsigned short* WfP  = (unsigned short*)(ws + 16646144);           //   262,144 B
    unsigned short* WfA  = (unsigned short*)(ws + 16908288);           //   262,144 B
    int*            meta = (int*)(ws + 17170432);                      //       256 B
    int*            list = (int*)(ws + 17170688);                      //   130,048 B
    int*            bc   = (int*)(ws + 17300736);                      //     8,000 B
    unsigned short* GT   = (unsigned short*)(ws + 17308736);           // 8,323,072 B
    float*          P    = (float*)(ws + 25631808);                    // 33,554,432 B
    // total ws ~59.2 MB

    k_count<<<NBLK, 256, 0, stream>>>(zp, bc);
    k_fillscan<<<NBLK, 256, 0, stream>>>(zp, bc, meta, list);
    k_prep<<<MAXCG + 128, 256, 0, stream>>>(x, zp, mask, sig,
                                            Wp1, bp1, Wa1, ba1, Wp2, Wa2,
                                            meta, list, HpS, HaS, GT, WfP, WfA);
    k_main<<<dim3(NBKT * KSPL, 8, 1), 512, 0, stream>>>(
        HpS, HaS, WfP, WfA, bp2, ba2, meta, GT, P);
    k_reduce<<<1024, 256, 0, stream>>>(P, (float*)d_out);
}